// Round 8
// baseline (368.763 us; speedup 1.0000x reference)
//
#include <hip/hip_runtime.h>
#include <hip/hip_bf16.h>

#define LAMBDA_INIT 0.78360576653162448f

typedef __attribute__((ext_vector_type(8))) short short8;
typedef __attribute__((ext_vector_type(4))) float f32x4;

__device__ __forceinline__ unsigned short f2bf(float f) {
  unsigned int u; __builtin_memcpy(&u, &f, 4);
  u += 0x7fffu + ((u >> 16) & 1u);
  return (unsigned short)(u >> 16);
}
// Native RTNE cast — compiler emits v_cvt_pk_bf16_f32 for pairs (m240).
__device__ __forceinline__ unsigned short f2bfn(float f) {
  __hip_bfloat16 h = __float2bfloat16(f);
  unsigned short u; __builtin_memcpy(&u, &h, 2);
  return u;
}
__device__ __forceinline__ short8 cvt8(float4 a, float4 b) {
  short8 s;
  s[0] = (short)f2bf(a.x); s[1] = (short)f2bf(a.y);
  s[2] = (short)f2bf(a.z); s[3] = (short)f2bf(a.w);
  s[4] = (short)f2bf(b.x); s[5] = (short)f2bf(b.y);
  s[6] = (short)f2bf(b.z); s[7] = (short)f2bf(b.w);
  return s;
}

// Async global->LDS, 16 B per lane, wave-uniform LDS base + lane*16.
#define GLOAD_LDS16(g, l)                                                     \
  __builtin_amdgcn_global_load_lds(                                           \
      (const __attribute__((address_space(1))) void*)(g),                     \
      (__attribute__((address_space(3))) void*)(l), 16, 0, 0)

// f32 -> bf16 bulk convert, 8 elems/thread (x only; fallback path).
__global__ void conv_bf16(const float* __restrict__ in,
                          unsigned short* __restrict__ outp, int n8) {
  const int i = blockIdx.x * 256 + threadIdx.x;
  if (i >= n8) return;
  const float4 a = *(const float4*)(in + (size_t)i * 8);
  const float4 b = *(const float4*)(in + (size_t)i * 8 + 4);
  *(short8*)(outp + (size_t)i * 8) = cvt8(a, b);
}

// Fused f32->bf16 convert of x + all four weights into ws (fast path).
__global__ void conv_all(const float* __restrict__ x, const float* __restrict__ wq,
                         const float* __restrict__ wk, const float* __restrict__ wv,
                         const float* __restrict__ wo, unsigned short* __restrict__ ws) {
  const int i = blockIdx.x * 256 + threadIdx.x;  // unit of 8 elems
  const float* src; size_t so; unsigned short* dst;
  if (i < 1048576)      { src = x;  so = i;           dst = ws; }
  else if (i < 1572864) { src = wq; so = i - 1048576; dst = ws + 8388608; }
  else if (i < 1835008) { src = wk; so = i - 1572864; dst = ws + 12582912; }
  else if (i < 2097152) { src = wv; so = i - 1835008; dst = ws + 14680064; }
  else                  { src = wo; so = i - 2097152; dst = ws + 16777216; }
  const float4 a = *(const float4*)(src + so * 8);
  const float4 b = *(const float4*)(src + so * 8 + 4);
  *(short8*)(dst + so * 8) = cvt8(a, b);
}

// ---------- Fast-path GEMMs: both operands bf16, staged via global_load_lds.
// XOR-swizzled LDS (round-7 proven: conflicts 2.5e7 -> ~0) + double-buffered
// prefetch (T3 minimum-2-phase, same barrier pattern attn has proven):
// STAGE(kt+1, other buf) issued BEFORE compute(kt), one barrier per k-tile,
// so the barrier's vmcnt drain lands after ~2000cy of compute instead of
// serializing the staging latency.

__global__ __launch_bounds__(256, 2)
void qkv_bb(const unsigned short* __restrict__ xb,
            const unsigned short* __restrict__ Wqb, const unsigned short* __restrict__ Wkb,
            const unsigned short* __restrict__ Wvb, const float* __restrict__ cosb,
            const float* __restrict__ sinb,
            unsigned short* __restrict__ Qb, unsigned short* __restrict__ Kb,
            unsigned short* __restrict__ Vtb) {
  __shared__ __align__(16) unsigned short As[2][128 * 64];
  __shared__ __align__(16) unsigned short Bs[2][128 * 64];
  const int t = threadIdx.x;
  const int wave = t >> 6, lane = t & 63;
  const int l15 = lane & 15, l4 = lane >> 4;
  const int wm = (wave >> 1) * 64, wn = (wave & 1) * 64;
  const int m0 = blockIdx.y * 128, n0 = blockIdx.x * 128;
  const int crow = t >> 3, ccol = (t & 7) * 8;
  const int swc = ccol ^ ((crow & 7) << 3);   // pre-swizzled source col
  const int rsw = (l15 & 7) << 3;             // fragment-read swizzle
  const unsigned short* Ag = xb + (size_t)m0 * 2048;

  const unsigned short* Bgh; int ntype;
  if (n0 < 2048)      { Bgh = Wqb + (size_t)n0 * 2048;          ntype = 0; }
  else if (n0 < 3072) { Bgh = Wkb + (size_t)(n0 - 2048) * 2048; ntype = 1; }
  else                { Bgh = Wvb + (size_t)(n0 - 3072) * 2048; ntype = 2; }

#define STAGE_AB(KT, BUF)                                                     \
  do {                                                                        \
    const int k0s = (KT) << 6;                                                \
    _Pragma("unroll")                                                         \
    for (int j_ = 0; j_ < 4; j_++) {                                          \
      GLOAD_LDS16(Ag + (size_t)(j_ * 32 + crow) * 2048 + k0s + swc,           \
                  &As[BUF][j_ * 2048 + wave * 512]);                          \
      GLOAD_LDS16(Bgh + (size_t)(j_ * 32 + crow) * 2048 + k0s + swc,          \
                  &Bs[BUF][j_ * 2048 + wave * 512]);                          \
    }                                                                         \
  } while (0)

  const f32x4 fzero = {0.f, 0.f, 0.f, 0.f};
  f32x4 acc[4][4];
#pragma unroll
  for (int i = 0; i < 4; i++)
#pragma unroll
    for (int j = 0; j < 4; j++) acc[i][j] = fzero;

  STAGE_AB(0, 0);
  for (int kt = 0; kt < 32; ++kt) {
    const int cur = kt & 1;
    __syncthreads();          // stage(kt) drained; prev compute reads done
    if (kt + 1 < 32) STAGE_AB(kt + 1, cur ^ 1);   // in flight during compute
    const unsigned short* Asb = &As[cur][0];
    const unsigned short* Bsb = &Bs[cur][0];
#pragma unroll
    for (int ks = 0; ks < 2; ++ks) {
      const int cb = (ks * 32 + l4 * 8) ^ rsw;
      short8 af[4], bfr[4];
#pragma unroll
      for (int mi = 0; mi < 4; mi++)
        af[mi] = *(const short8*)(&Asb[(wm + mi * 16 + l15) * 64 + cb]);
#pragma unroll
      for (int ni = 0; ni < 4; ni++)
        bfr[ni] = *(const short8*)(&Bsb[(wn + ni * 16 + l15) * 64 + cb]);
#pragma unroll
      for (int mi = 0; mi < 4; mi++)
#pragma unroll
        for (int ni = 0; ni < 4; ni++)
          acc[mi][ni] = __builtin_amdgcn_mfma_f32_16x16x32_bf16(af[mi], bfr[ni], acc[mi][ni], 0, 0, 0);
    }
  }
#undef STAGE_AB
#pragma unroll
  for (int mi = 0; mi < 4; mi++)
#pragma unroll
    for (int ni = 0; ni < 4; ni++)
#pragma unroll
      for (int r = 0; r < 4; r++) {
        const int m = m0 + wm + mi * 16 + l4 * 4 + r;
        const int n = n0 + wn + ni * 16 + l15;
        float fv = acc[mi][ni][r];
        if (ntype < 2) {
          const int s = m & 2047;
          const int j = (n & 63) >> 1;
          const float c = cosb[s * 32 + j];
          const float sn = sinb[s * 32 + j];
          const float p = __shfl_xor(fv, 1);
          fv = (n & 1) ? (p * sn + fv * c) : (fv * c - p * sn);
        }
        if (ntype == 0)
          Qb[(size_t)m * 2048 + n] = f2bf(fv);
        else if (ntype == 1)
          Kb[(size_t)m * 1024 + (n - 2048)] = f2bf(fv);
        else
          Vtb[((size_t)((m >> 11) * 1024 + (n - 3072))) * 2048 + (m & 2047)] = f2bf(fv);
      }
}

// O-projection, both operands bf16, C f32.
__global__ __launch_bounds__(256, 2)
void o_bb(const unsigned short* __restrict__ Ab, const unsigned short* __restrict__ Wob,
          float* __restrict__ C) {
  __shared__ __align__(16) unsigned short As[2][128 * 64];
  __shared__ __align__(16) unsigned short Bs[2][128 * 64];
  const int t = threadIdx.x;
  const int wave = t >> 6, lane = t & 63;
  const int l15 = lane & 15, l4 = lane >> 4;
  const int wm = (wave >> 1) * 64, wn = (wave & 1) * 64;
  const int m0 = blockIdx.y * 128, n0 = blockIdx.x * 128;
  const int crow = t >> 3, ccol = (t & 7) * 8;
  const int swc = ccol ^ ((crow & 7) << 3);
  const int rsw = (l15 & 7) << 3;
  const unsigned short* Ag = Ab + (size_t)m0 * 2048;
  const unsigned short* Bgh = Wob + (size_t)n0 * 2048;

#define STAGE_AB(KT, BUF)                                                     \
  do {                                                                        \
    const int k0s = (KT) << 6;                                                \
    _Pragma("unroll")                                                         \
    for (int j_ = 0; j_ < 4; j_++) {                                          \
      GLOAD_LDS16(Ag + (size_t)(j_ * 32 + crow) * 2048 + k0s + swc,           \
                  &As[BUF][j_ * 2048 + wave * 512]);                          \
      GLOAD_LDS16(Bgh + (size_t)(j_ * 32 + crow) * 2048 + k0s + swc,          \
                  &Bs[BUF][j_ * 2048 + wave * 512]);                          \
    }                                                                         \
  } while (0)

  const f32x4 fzero = {0.f, 0.f, 0.f, 0.f};
  f32x4 acc[4][4];
#pragma unroll
  for (int i = 0; i < 4; i++)
#pragma unroll
    for (int j = 0; j < 4; j++) acc[i][j] = fzero;

  STAGE_AB(0, 0);
  for (int kt = 0; kt < 32; ++kt) {
    const int cur = kt & 1;
    __syncthreads();
    if (kt + 1 < 32) STAGE_AB(kt + 1, cur ^ 1);
    const unsigned short* Asb = &As[cur][0];
    const unsigned short* Bsb = &Bs[cur][0];
#pragma unroll
    for (int ks = 0; ks < 2; ++ks) {
      const int cb = (ks * 32 + l4 * 8) ^ rsw;
      short8 af[4], bfr[4];
#pragma unroll
      for (int mi = 0; mi < 4; mi++)
        af[mi] = *(const short8*)(&Asb[(wm + mi * 16 + l15) * 64 + cb]);
#pragma unroll
      for (int ni = 0; ni < 4; ni++)
        bfr[ni] = *(const short8*)(&Bsb[(wn + ni * 16 + l15) * 64 + cb]);
#pragma unroll
      for (int mi = 0; mi < 4; mi++)
#pragma unroll
        for (int ni = 0; ni < 4; ni++)
          acc[mi][ni] = __builtin_amdgcn_mfma_f32_16x16x32_bf16(af[mi], bfr[ni], acc[mi][ni], 0, 0, 0);
    }
  }
#undef STAGE_AB
#pragma unroll
  for (int mi = 0; mi < 4; mi++)
#pragma unroll
    for (int ni = 0; ni < 4; ni++)
#pragma unroll
      for (int r = 0; r < 4; r++) {
        const int m = m0 + wm + mi * 16 + l4 * 4 + r;
        const int n = n0 + wn + ni * 16 + l15;
        C[(size_t)m * 2048 + n] = acc[mi][ni][r];
      }
}

// ---------- Fallback GEMMs (round-6 proven): B from f32 weights.

__global__ __launch_bounds__(256, 2)
void qkv_gemm_f32(const unsigned short* __restrict__ xb,
                  const float* __restrict__ Wq, const float* __restrict__ Wk,
                  const float* __restrict__ Wv, const float* __restrict__ cosb,
                  const float* __restrict__ sinb,
                  unsigned short* __restrict__ Qb, unsigned short* __restrict__ Kb,
                  unsigned short* __restrict__ Vtb) {
  __shared__ __align__(16) unsigned short As[128 * 64];
  __shared__ __align__(16) unsigned short Bs[128 * 72];
  const int t = threadIdx.x;
  const int wave = t >> 6, lane = t & 63;
  const int l15 = lane & 15, l4 = lane >> 4;
  const int wm = (wave >> 1) * 64, wn = (wave & 1) * 64;
  const int m0 = blockIdx.y * 128, n0 = blockIdx.x * 128;
  const int crow = t >> 3, ccol = (t & 7) * 8;
  const unsigned short* Ag = xb + (size_t)m0 * 2048;

  const float* Bg; int ntype;
  if (n0 < 2048)      { Bg = Wq + (size_t)n0 * 2048;          ntype = 0; }
  else if (n0 < 3072) { Bg = Wk + (size_t)(n0 - 2048) * 2048; ntype = 1; }
  else                { Bg = Wv + (size_t)(n0 - 3072) * 2048; ntype = 2; }

  const f32x4 fzero = {0.f, 0.f, 0.f, 0.f};
  f32x4 acc[4][4];
#pragma unroll
  for (int i = 0; i < 4; i++)
#pragma unroll
    for (int j = 0; j < 4; j++) acc[i][j] = fzero;

  float4 rbf[4][2];
#pragma unroll
  for (int i = 0; i < 4; i++) {
    rbf[i][0] = *(const float4*)(Bg + (size_t)(crow + 32 * i) * 2048 + ccol);
    rbf[i][1] = *(const float4*)(Bg + (size_t)(crow + 32 * i) * 2048 + ccol + 4);
  }
  for (int kt = 0; kt < 32; ++kt) {
    const int k0 = kt << 6;
    __syncthreads();
#pragma unroll
    for (int j = 0; j < 4; j++)
      GLOAD_LDS16(Ag + (size_t)(j * 32 + crow) * 2048 + k0 + ccol,
                  &As[j * 2048 + wave * 512]);
#pragma unroll
    for (int i = 0; i < 4; i++)
      *(short8*)(&Bs[(crow + 32 * i) * 72 + ccol]) = cvt8(rbf[i][0], rbf[i][1]);
    __syncthreads();
    if (kt + 1 < 32) {
      const int kn = k0 + 64;
#pragma unroll
      for (int i = 0; i < 4; i++) {
        rbf[i][0] = *(const float4*)(Bg + (size_t)(crow + 32 * i) * 2048 + kn + ccol);
        rbf[i][1] = *(const float4*)(Bg + (size_t)(crow + 32 * i) * 2048 + kn + ccol + 4);
      }
    }
#pragma unroll
    for (int ks = 0; ks < 2; ++ks) {
      short8 af[4], bfr[4];
#pragma unroll
      for (int mi = 0; mi < 4; mi++)
        af[mi] = *(const short8*)(&As[(wm + mi * 16 + l15) * 64 + ks * 32 + l4 * 8]);
#pragma unroll
      for (int ni = 0; ni < 4; ni++)
        bfr[ni] = *(const short8*)(&Bs[(wn + ni * 16 + l15) * 72 + ks * 32 + l4 * 8]);
#pragma unroll
      for (int mi = 0; mi < 4; mi++)
#pragma unroll
        for (int ni = 0; ni < 4; ni++)
          acc[mi][ni] = __builtin_amdgcn_mfma_f32_16x16x32_bf16(af[mi], bfr[ni], acc[mi][ni], 0, 0, 0);
    }
  }
#pragma unroll
  for (int mi = 0; mi < 4; mi++)
#pragma unroll
    for (int ni = 0; ni < 4; ni++)
#pragma unroll
      for (int r = 0; r < 4; r++) {
        const int m = m0 + wm + mi * 16 + l4 * 4 + r;
        const int n = n0 + wn + ni * 16 + l15;
        float fv = acc[mi][ni][r];
        if (ntype < 2) {
          const int s = m & 2047;
          const int j = (n & 63) >> 1;
          const float c = cosb[s * 32 + j];
          const float sn = sinb[s * 32 + j];
          const float p = __shfl_xor(fv, 1);
          fv = (n & 1) ? (p * sn + fv * c) : (fv * c - p * sn);
        }
        if (ntype == 0)
          Qb[(size_t)m * 2048 + n] = f2bf(fv);
        else if (ntype == 1)
          Kb[(size_t)m * 1024 + (n - 2048)] = f2bf(fv);
        else
          Vtb[((size_t)((m >> 11) * 1024 + (n - 3072))) * 2048 + (m & 2047)] = f2bf(fv);
      }
}

__global__ __launch_bounds__(256, 2)
void o_gemm_f32(const unsigned short* __restrict__ Ab, const float* __restrict__ Wo,
                float* __restrict__ C) {
  __shared__ __align__(16) unsigned short As[128 * 64];
  __shared__ __align__(16) unsigned short Bs[128 * 72];
  const int t = threadIdx.x;
  const int wave = t >> 6, lane = t & 63;
  const int l15 = lane & 15, l4 = lane >> 4;
  const int wm = (wave >> 1) * 64, wn = (wave & 1) * 64;
  const int m0 = blockIdx.y * 128, n0 = blockIdx.x * 128;
  const int crow = t >> 3, ccol = (t & 7) * 8;
  const unsigned short* Ag = Ab + (size_t)m0 * 2048;
  const float* Bg = Wo + (size_t)n0 * 2048;

  const f32x4 fzero = {0.f, 0.f, 0.f, 0.f};
  f32x4 acc[4][4];
#pragma unroll
  for (int i = 0; i < 4; i++)
#pragma unroll
    for (int j = 0; j < 4; j++) acc[i][j] = fzero;

  float4 rbf[4][2];
#pragma unroll
  for (int i = 0; i < 4; i++) {
    rbf[i][0] = *(const float4*)(Bg + (size_t)(crow + 32 * i) * 2048 + ccol);
    rbf[i][1] = *(const float4*)(Bg + (size_t)(crow + 32 * i) * 2048 + ccol + 4);
  }
  for (int kt = 0; kt < 32; ++kt) {
    const int k0 = kt << 6;
    __syncthreads();
#pragma unroll
    for (int j = 0; j < 4; j++)
      GLOAD_LDS16(Ag + (size_t)(j * 32 + crow) * 2048 + k0 + ccol,
                  &As[j * 2048 + wave * 512]);
#pragma unroll
    for (int i = 0; i < 4; i++)
      *(short8*)(&Bs[(crow + 32 * i) * 72 + ccol]) = cvt8(rbf[i][0], rbf[i][1]);
    __syncthreads();
    if (kt + 1 < 32) {
      const int kn = k0 + 64;
#pragma unroll
      for (int i = 0; i < 4; i++) {
        rbf[i][0] = *(const float4*)(Bg + (size_t)(crow + 32 * i) * 2048 + kn + ccol);
        rbf[i][1] = *(const float4*)(Bg + (size_t)(crow + 32 * i) * 2048 + kn + ccol + 4);
      }
    }
#pragma unroll
    for (int ks = 0; ks < 2; ++ks) {
      short8 af[4], bfr[4];
#pragma unroll
      for (int mi = 0; mi < 4; mi++)
        af[mi] = *(const short8*)(&As[(wm + mi * 16 + l15) * 64 + ks * 32 + l4 * 8]);
#pragma unroll
      for (int ni = 0; ni < 4; ni++)
        bfr[ni] = *(const short8*)(&Bs[(wn + ni * 16 + l15) * 72 + ks * 32 + l4 * 8]);
#pragma unroll
      for (int mi = 0; mi < 4; mi++)
#pragma unroll
        for (int ni = 0; ni < 4; ni++)
          acc[mi][ni] = __builtin_amdgcn_mfma_f32_16x16x32_bf16(af[mi], bfr[ni], acc[mi][ni], 0, 0, 0);
    }
  }
#pragma unroll
  for (int mi = 0; mi < 4; mi++)
#pragma unroll
    for (int ni = 0; ni < 4; ni++)
#pragma unroll
      for (int r = 0; r < 4; r++) {
        const int m = m0 + wm + mi * 16 + l4 * 4 + r;
        const int n = n0 + wn + ni * 16 + l15;
        C[(size_t)m * 2048 + n] = acc[mi][ni][r];
      }
}

// ---------- Fused differential flash attention (round-7 proven, unchanged).
__global__ __launch_bounds__(256, 2)
void attn_kernel(const unsigned short* __restrict__ Q,
                 const unsigned short* __restrict__ Kb,
                 const unsigned short* __restrict__ Vt,
                 unsigned short* __restrict__ Ab,
                 const float* __restrict__ lq1,
                 const float* __restrict__ lk1,
                 const float* __restrict__ lq2,
                 const float* __restrict__ lk2,
                 const float* __restrict__ wsub) {
  // Bijective XCD swizzle (512 blocks = 8 XCDs x 64): dispatch d -> work
  // w = (d%8)*64 + d/8, so each XCD owns 64 consecutive work ids = 2 full
  // (b,hk) K/V groups -> K/V fetched ~once per XCD.
  const int flat = blockIdx.y * 16 + blockIdx.x;
  const int w = ((flat & 7) << 6) | (flat >> 3);
  const int pi = w & 15;                     // 0..15
  const int bh = w >> 4;                     // b*16 + h
  const int b = bh >> 4, h = bh & 15, hk = h >> 1;

  __shared__ __align__(16) unsigned short Ks[2][2][64 * 64];  // [buf][c][kv][d]
  __shared__ __align__(16) unsigned short Vs[2][128 * 64];    // [buf][d][kv]
  __shared__ __align__(16) unsigned short Ps[64 * 64];        // [q][kv]

  const int t = threadIdx.x;                 // 0..255
  const int wave = t >> 6, lane = t & 63;
  const int l15 = lane & 15, l4 = lane >> 4;
  const int crow = t >> 3, ccol = (t & 7) * 8;   // crow 0..31
  const int swc = ccol ^ ((crow & 7) << 3);  // pre-swizzled source col for staging

  float s1 = 0.f, s2 = 0.f;
  for (int i = 0; i < 64; i++) {
    s1 += lq1[i] * lk1[i];
    s2 += lq2[i] * lk2[i];
  }
  const float lam = __expf(s1) - __expf(s2) + LAMBDA_INIT;

  float wv[8];
#pragma unroll
  for (int nt = 0; nt < 8; nt++) wv[nt] = wsub[nt * 16 + l15];

  // ones B-fragment: B[k][n] = (n==0) ? 1 : 0  (bf16 1.0 = 0x3F80)
  short8 onesf;
#pragma unroll
  for (int j = 0; j < 8; j++) onesf[j] = (l15 == 0) ? (short)0x3F80 : (short)0;

  const f32x4 fzero = {0.f, 0.f, 0.f, 0.f};
  const unsigned short* Kgb = Kb + ((size_t)(b * 2048)) * 1024 + 2 * hk * 64;
  const unsigned short* Vgb = Vt + ((size_t)((b * 8 + hk) * 128)) * 2048;

#define STAGE_KV(KT, BUF)                                                     \
  do {                                                                        \
    const int k0s = (KT) << 6;                                                \
    _Pragma("unroll")                                                         \
    for (int c_ = 0; c_ < 2; c_++)                                            \
      _Pragma("unroll")                                                       \
      for (int i_ = 0; i_ < 2; i_++)                                          \
        GLOAD_LDS16(Kgb + (size_t)(k0s + i_ * 32 + crow) * 1024 + c_ * 64 + swc, \
                    &Ks[BUF][c_][i_ * 2048 + wave * 512]);                    \
    _Pragma("unroll")                                                         \
    for (int i_ = 0; i_ < 4; i_++)                                            \
      GLOAD_LDS16(Vgb + (size_t)(i_ * 32 + crow) * 2048 + k0s + swc,          \
                  &Vs[BUF][i_ * 2048 + wave * 512]);                          \
  } while (0)

  for (int half = 0; half < 2; ++half) {
    const int qi = half ? (31 - pi) : pi;    // both halves together: 33 k-tiles/block
    const int q0 = qi * 64;
    const int nkt = qi + 1;

    // Q fragments, direct global->reg (rows are wave-exclusive: wave*16..+15).
    short8 qf[2][2];  // [c][ks]
#pragma unroll
    for (int c = 0; c < 2; c++)
#pragma unroll
      for (int ks = 0; ks < 2; ks++)
        qf[c][ks] = *(const short8*)(Q + ((size_t)(b * 2048 + q0 + wave * 16 + l15)) * 2048
                                       + (2 * h + c) * 64 + ks * 32 + l4 * 8);

    f32x4 accO[2][8];  // [c][nt]
    f32x4 accL[2];
#pragma unroll
    for (int c = 0; c < 2; c++) {
      accL[c] = fzero;
#pragma unroll
      for (int nt = 0; nt < 8; nt++) accO[c][nt] = fzero;
    }

    __syncthreads();          // prior half's readers done before buf0 overwrite
    STAGE_KV(0, 0);

    for (int kt = 0; kt < nkt; ++kt) {
      const int cur = kt & 1;
      __syncthreads();        // stage(kt) complete; prev compute's reads done
      if (kt + 1 < nkt) STAGE_KV(kt + 1, cur ^ 1);   // in flight during compute(kt)

      const unsigned short* Ksb0 = &Ks[cur][0][0];
      const unsigned short* Ksb1 = &Ks[cur][1][0];
      const unsigned short* Vsb  = &Vs[cur][0];
      const bool diag = (kt == qi);          // block-uniform

      // ---- QK^T -> softmax numerator -> P (LDS, wave-local rows) -> pf frags
      short8 pf[2][2];  // [c][ks]
      const int rbase = wave * 16 + l4 * 4;
      const int sw0 = (rbase & 7) << 3;      // rbase&7 in {0,4}
#pragma unroll
      for (int c = 0; c < 2; c++) {
        const unsigned short* Ksb = c ? Ksb1 : Ksb0;
#pragma unroll
        for (int ct = 0; ct < 4; ct++) {
          const int kr = ct * 16 + l15;
          const int ksw = (kr & 7) << 3;
          const short8 kb0 = *(const short8*)(&Ksb[kr * 64 + ((l4 * 8) ^ ksw)]);
          const short8 kb1 = *(const short8*)(&Ksb[kr * 64 + ((32 + l4 * 8) ^ ksw)]);
          f32x4 z = fzero;
          z = __builtin_amdgcn_mfma_f32_16x16x32_bf16(qf[c][0], kb0, z, 0, 0, 0);
          z = __builtin_amdgcn_mfma_f32_16x16x32_bf16(qf[c][1], kb1, z, 0, 0, 0);
          float e[4];
#pragma unroll
          for (int r = 0; r < 4; r++)
            // exp(0.125*z - 16) as exp2(z*0.125*log2e - 16*log2e)
            e[r] = exp2f(fmaf(z[r], 0.18033688011112042f, -23.083120654223414f));
          if (diag) {                        // uniform branch; k0 == q0 cancels
#pragma unroll
            for (int r = 0; r < 4; r++)
              if ((ct * 16 + l15) > (rbase + r)) e[r] = 0.f;
          }
          // prow&7 = (rbase&7)|r with no carry -> swizzle = sw0 ^ (r<<3)
          const int colsw = (ct * 16 + l15) ^ sw0;
#pragma unroll
          for (int r = 0; r < 4; r++)
            Ps[(rbase + r) * 64 + (colsw ^ (r << 3))] = f2bfn(e[r]);
        }
        // Wave-local P round-trip (rows [wave*16, wave*16+16) exclusive to wave).
        {
          const int prow = wave * 16 + l15;
          const int psw = (l15 & 7) << 3;
#pragma unroll
          for (int ks = 0; ks < 2; ks++)
            pf[c][ks] = *(const short8*)(&Ps[prow * 64 + ((ks * 32 + l4 * 8) ^ psw)]);
        }
      }

      // ---- PV + row sums
      __builtin_amdgcn_s_setprio(1);
#pragma unroll
      for (int nt = 0; nt < 8; nt++) {
        const int vrow = nt * 16 + l15;
        const int vsw = (vrow & 7) << 3;
        const short8 v0 = *(const short8*)(&Vsb[vrow * 64 + ((l4 * 8) ^ vsw)]);
        const short8 v1 = *(const short8*)(&Vsb[vrow * 64 + ((32 + l4 * 8) ^ vsw)]);
        accO[0][nt] = __builtin_amdgcn_mfma_f32_16x16x32_bf16(pf[0][0], v0, accO[0][nt], 0, 0, 0);
        accO[0][nt] = __builtin_amdgcn_mfma_f32_16x16x32_bf16(pf[0][1], v1, accO[0][nt], 0, 0, 0);
        accO[1][nt] = __builtin_amdgcn_mfma_f32_16x16x32_bf16(pf[1][0], v0, accO[1][nt], 0, 0, 0);
        accO[1][nt] = __builtin_amdgcn_mfma_f32_16x16x32_bf16(pf[1][1], v1, accO[1][nt], 0, 0, 0);
      }
#pragma unroll
      for (int c = 0; c < 2; c++) {
        accL[c] = __builtin_amdgcn_mfma_f32_16x16x32_bf16(pf[c][0], onesf, accL[c], 0, 0, 0);
        accL[c] = __builtin_amdgcn_mfma_f32_16x16x32_bf16(pf[c][1], onesf, accL[c], 0, 0, 0);
      }
      __builtin_amdgcn_s_setprio(0);
    }

    // Epilogue: o1 - lam*o2, RMS-norm over 128, * subln_w * (1 - lambda_init).
#pragma unroll
    for (int r = 0; r < 4; r++) {
      const float l1 = __shfl(accL[0][r], lane & 48);
      const float l2 = __shfl(accL[1][r], lane & 48);
      const float i1 = 1.f / fmaxf(l1, 1e-30f);
      const float i2 = lam / fmaxf(l2, 1e-30f);
      float av[8], ss = 0.f;
#pragma unroll
      for (int nt = 0; nt < 8; nt++) {
        const float a = accO[0][nt][r] * i1 - accO[1][nt][r] * i2;
        av[nt] = a;
        ss += a * a;
      }
#pragma unroll
      for (int off = 1; off < 16; off <<= 1) ss += __shfl_xor(ss, off, 16);
      const float sca = rsqrtf(ss * (1.f / 128.f) + 1e-5f) * (1.f - LAMBDA_INIT);
      const int qrow = q0 + wave * 16 + l4 * 4 + r;
      unsigned short* Ao = Ab + ((size_t)(b * 2048 + qrow)) * 2048 + h * 128;
#pragma unroll
      for (int nt = 0; nt < 8; nt++)
        Ao[nt * 16 + l15] = f2bfn(av[nt] * sca * wv[nt]);
    }
  }
#undef STAGE_KV
}

extern "C" void kernel_launch(void* const* d_in, const int* in_sizes, int n_in,
                              void* d_out, int out_size, void* d_ws, size_t ws_size,
                              hipStream_t stream) {
  const float* x    = (const float*)d_in[0];
  const float* cosb = (const float*)d_in[1];
  const float* sinb = (const float*)d_in[2];
  const float* Wq   = (const float*)d_in[3];
  const float* Wk   = (const float*)d_in[4];
  const float* Wv   = (const float*)d_in[5];
  const float* Wo   = (const float*)d_in[6];
  const float* lq1  = (const float*)d_in[7];
  const float* lk1  = (const float*)d_in[8];
  const float* lq2  = (const float*)d_in[9];
  const float* lk2  = (const float*)d_in[10];
  const float* wsub = (const float*)d_in[11];
  float* out = (float*)d_out;

  // ws layout (fast, ws>=40MiB): [0,16) xb -> later A | [16,24) Wqb | [24,28) Wkb
  //   | [28,32) Wvb | [32,40) Wob.  Fallback (ws>=16MiB): [0,16) xb -> A.
  // d_out (32 MiB f32) temporarily hosts bf16 K(8) | Vt(8) | Q(16); O-GEMM
  // overwrites d_out with f32 C (K/Vt/Q dead by then).
  unsigned short* XA  = (unsigned short*)d_ws;
  unsigned short* Kb  = (unsigned short*)d_out;
  unsigned short* Vtb = Kb + (size_t)4096 * 1024;
  unsigned short* Qb  = Vtb + (size_t)2 * 1024 * 2048;

  dim3 blk(256);
  if (ws_size >= (size_t)41943040) {
    unsigned short* Wqb = XA + 8388608;
    unsigned short* Wkb = XA + 12582912;
    unsigned short* Wvb = XA + 14680064;
    unsigned short* Wob = XA + 16777216;
    conv_all<<<10240, blk, 0, stream>>>(x, Wq, Wk, Wv, Wo, XA);
    qkv_bb<<<dim3(32, 32), blk, 0, stream>>>(XA, Wqb, Wkb, Wvb, cosb, sinb, Qb, Kb, Vtb);
    attn_kernel<<<dim3(16, 32), blk, 0, stream>>>(Qb, Kb, Vtb, XA, lq1, lk1, lq2, lk2, wsub);
    o_bb<<<dim3(16, 32), blk, 0, stream>>>(XA, Wob, out);
  } else {
    conv_bf16<<<4096, blk, 0, stream>>>(x, XA, 1048576);
    qkv_gemm_f32<<<dim3(32, 32), blk, 0, stream>>>(XA, Wq, Wk, Wv, cosb, sinb, Qb, Kb, Vtb);
    attn_kernel<<<dim3(16, 32), blk, 0, stream>>>(Qb, Kb, Vtb, XA, lq1, lk1, lq2, lk2, wsub);
    o_gemm_f32<<<dim3(16, 32), blk, 0, stream>>>(XA, Wo, out);
  }
}

// Round 9
// 362.406 us; speedup vs baseline: 1.0175x; 1.0175x over previous
//
#include <hip/hip_runtime.h>
#include <hip/hip_bf16.h>

#define LAMBDA_INIT 0.78360576653162448f

typedef __attribute__((ext_vector_type(8))) short short8;
typedef __attribute__((ext_vector_type(4))) float f32x4;

__device__ __forceinline__ unsigned short f2bf(float f) {
  unsigned int u; __builtin_memcpy(&u, &f, 4);
  u += 0x7fffu + ((u >> 16) & 1u);
  return (unsigned short)(u >> 16);
}
// Native RTNE cast — compiler emits v_cvt_pk_bf16_f32 for pairs (m240).
__device__ __forceinline__ unsigned short f2bfn(float f) {
  __hip_bfloat16 h = __float2bfloat16(f);
  unsigned short u; __builtin_memcpy(&u, &h, 2);
  return u;
}
__device__ __forceinline__ short8 cvt8(float4 a, float4 b) {
  short8 s;
  s[0] = (short)f2bf(a.x); s[1] = (short)f2bf(a.y);
  s[2] = (short)f2bf(a.z); s[3] = (short)f2bf(a.w);
  s[4] = (short)f2bf(b.x); s[5] = (short)f2bf(b.y);
  s[6] = (short)f2bf(b.z); s[7] = (short)f2bf(b.w);
  return s;
}

// Async global->LDS, 16 B per lane, wave-uniform LDS base + lane*16.
#define GLOAD_LDS16(g, l)                                                     \
  __builtin_amdgcn_global_load_lds(                                           \
      (const __attribute__((address_space(1))) void*)(g),                     \
      (__attribute__((address_space(3))) void*)(l), 16, 0, 0)

// f32 -> bf16 bulk convert, 8 elems/thread (x only; fallback path).
__global__ void conv_bf16(const float* __restrict__ in,
                          unsigned short* __restrict__ outp, int n8) {
  const int i = blockIdx.x * 256 + threadIdx.x;
  if (i >= n8) return;
  const float4 a = *(const float4*)(in + (size_t)i * 8);
  const float4 b = *(const float4*)(in + (size_t)i * 8 + 4);
  *(short8*)(outp + (size_t)i * 8) = cvt8(a, b);
}

// Fused f32->bf16 convert of x + all four weights into ws (fast path).
__global__ void conv_all(const float* __restrict__ x, const float* __restrict__ wq,
                         const float* __restrict__ wk, const float* __restrict__ wv,
                         const float* __restrict__ wo, unsigned short* __restrict__ ws) {
  const int i = blockIdx.x * 256 + threadIdx.x;  // unit of 8 elems
  const float* src; size_t so; unsigned short* dst;
  if (i < 1048576)      { src = x;  so = i;           dst = ws; }
  else if (i < 1572864) { src = wq; so = i - 1048576; dst = ws + 8388608; }
  else if (i < 1835008) { src = wk; so = i - 1572864; dst = ws + 12582912; }
  else if (i < 2097152) { src = wv; so = i - 1835008; dst = ws + 14680064; }
  else                  { src = wo; so = i - 2097152; dst = ws + 16777216; }
  const float4 a = *(const float4*)(src + so * 8);
  const float4 b = *(const float4*)(src + so * 8 + 4);
  *(short8*)(dst + so * 8) = cvt8(a, b);
}

// ---------- Fast-path GEMMs (round-7 proven: 1-phase + XOR swizzle).
// Round-8 lesson: dbuf traded the 3rd co-resident block (TLP) for intra-block
// overlap — net neutral. 1-phase + 32KB LDS keeps occupancy ~33%.

__global__ __launch_bounds__(256, 2)
void qkv_bb(const unsigned short* __restrict__ xb,
            const unsigned short* __restrict__ Wqb, const unsigned short* __restrict__ Wkb,
            const unsigned short* __restrict__ Wvb, const float* __restrict__ cosb,
            const float* __restrict__ sinb,
            unsigned short* __restrict__ Qb, unsigned short* __restrict__ Kb,
            unsigned short* __restrict__ Vtb) {
  __shared__ __align__(16) unsigned short As[128 * 64];
  __shared__ __align__(16) unsigned short Bs[128 * 64];
  const int t = threadIdx.x;
  const int wave = t >> 6, lane = t & 63;
  const int l15 = lane & 15, l4 = lane >> 4;
  const int wm = (wave >> 1) * 64, wn = (wave & 1) * 64;
  const int m0 = blockIdx.y * 128, n0 = blockIdx.x * 128;
  const int crow = t >> 3, ccol = (t & 7) * 8;
  const int swc = ccol ^ ((crow & 7) << 3);   // pre-swizzled source col
  const int rsw = (l15 & 7) << 3;             // fragment-read swizzle
  const unsigned short* Ag = xb + (size_t)m0 * 2048;

  const unsigned short* Bgh; int ntype;
  if (n0 < 2048)      { Bgh = Wqb + (size_t)n0 * 2048;          ntype = 0; }
  else if (n0 < 3072) { Bgh = Wkb + (size_t)(n0 - 2048) * 2048; ntype = 1; }
  else                { Bgh = Wvb + (size_t)(n0 - 3072) * 2048; ntype = 2; }

  const f32x4 fzero = {0.f, 0.f, 0.f, 0.f};
  f32x4 acc[4][4];
#pragma unroll
  for (int i = 0; i < 4; i++)
#pragma unroll
    for (int j = 0; j < 4; j++) acc[i][j] = fzero;

  for (int kt = 0; kt < 32; ++kt) {
    const int k0 = kt << 6;
    __syncthreads();
#pragma unroll
    for (int j = 0; j < 4; j++) {
      GLOAD_LDS16(Ag + (size_t)(j * 32 + crow) * 2048 + k0 + swc,
                  &As[j * 2048 + wave * 512]);
      GLOAD_LDS16(Bgh + (size_t)(j * 32 + crow) * 2048 + k0 + swc,
                  &Bs[j * 2048 + wave * 512]);
    }
    __syncthreads();
#pragma unroll
    for (int ks = 0; ks < 2; ++ks) {
      const int cb = (ks * 32 + l4 * 8) ^ rsw;
      short8 af[4], bfr[4];
#pragma unroll
      for (int mi = 0; mi < 4; mi++)
        af[mi] = *(const short8*)(&As[(wm + mi * 16 + l15) * 64 + cb]);
#pragma unroll
      for (int ni = 0; ni < 4; ni++)
        bfr[ni] = *(const short8*)(&Bs[(wn + ni * 16 + l15) * 64 + cb]);
#pragma unroll
      for (int mi = 0; mi < 4; mi++)
#pragma unroll
        for (int ni = 0; ni < 4; ni++)
          acc[mi][ni] = __builtin_amdgcn_mfma_f32_16x16x32_bf16(af[mi], bfr[ni], acc[mi][ni], 0, 0, 0);
    }
  }
#pragma unroll
  for (int mi = 0; mi < 4; mi++)
#pragma unroll
    for (int ni = 0; ni < 4; ni++)
#pragma unroll
      for (int r = 0; r < 4; r++) {
        const int m = m0 + wm + mi * 16 + l4 * 4 + r;
        const int n = n0 + wn + ni * 16 + l15;
        float fv = acc[mi][ni][r];
        if (ntype < 2) {
          const int s = m & 2047;
          const int j = (n & 63) >> 1;
          const float c = cosb[s * 32 + j];
          const float sn = sinb[s * 32 + j];
          const float p = __shfl_xor(fv, 1);
          fv = (n & 1) ? (p * sn + fv * c) : (fv * c - p * sn);
        }
        if (ntype == 0)
          Qb[(size_t)m * 2048 + n] = f2bf(fv);
        else if (ntype == 1)
          Kb[(size_t)m * 1024 + (n - 2048)] = f2bf(fv);
        else
          Vtb[((size_t)((m >> 11) * 1024 + (n - 3072))) * 2048 + (m & 2047)] = f2bf(fv);
      }
}

// O-projection, both operands bf16, C f32.
__global__ __launch_bounds__(256, 2)
void o_bb(const unsigned short* __restrict__ Ab, const unsigned short* __restrict__ Wob,
          float* __restrict__ C) {
  __shared__ __align__(16) unsigned short As[128 * 64];
  __shared__ __align__(16) unsigned short Bs[128 * 64];
  const int t = threadIdx.x;
  const int wave = t >> 6, lane = t & 63;
  const int l15 = lane & 15, l4 = lane >> 4;
  const int wm = (wave >> 1) * 64, wn = (wave & 1) * 64;
  const int m0 = blockIdx.y * 128, n0 = blockIdx.x * 128;
  const int crow = t >> 3, ccol = (t & 7) * 8;
  const int swc = ccol ^ ((crow & 7) << 3);
  const int rsw = (l15 & 7) << 3;
  const unsigned short* Ag = Ab + (size_t)m0 * 2048;
  const unsigned short* Bgh = Wob + (size_t)n0 * 2048;

  const f32x4 fzero = {0.f, 0.f, 0.f, 0.f};
  f32x4 acc[4][4];
#pragma unroll
  for (int i = 0; i < 4; i++)
#pragma unroll
    for (int j = 0; j < 4; j++) acc[i][j] = fzero;

  for (int kt = 0; kt < 32; ++kt) {
    const int k0 = kt << 6;
    __syncthreads();
#pragma unroll
    for (int j = 0; j < 4; j++) {
      GLOAD_LDS16(Ag + (size_t)(j * 32 + crow) * 2048 + k0 + swc,
                  &As[j * 2048 + wave * 512]);
      GLOAD_LDS16(Bgh + (size_t)(j * 32 + crow) * 2048 + k0 + swc,
                  &Bs[j * 2048 + wave * 512]);
    }
    __syncthreads();
#pragma unroll
    for (int ks = 0; ks < 2; ++ks) {
      const int cb = (ks * 32 + l4 * 8) ^ rsw;
      short8 af[4], bfr[4];
#pragma unroll
      for (int mi = 0; mi < 4; mi++)
        af[mi] = *(const short8*)(&As[(wm + mi * 16 + l15) * 64 + cb]);
#pragma unroll
      for (int ni = 0; ni < 4; ni++)
        bfr[ni] = *(const short8*)(&Bs[(wn + ni * 16 + l15) * 64 + cb]);
#pragma unroll
      for (int mi = 0; mi < 4; mi++)
#pragma unroll
        for (int ni = 0; ni < 4; ni++)
          acc[mi][ni] = __builtin_amdgcn_mfma_f32_16x16x32_bf16(af[mi], bfr[ni], acc[mi][ni], 0, 0, 0);
    }
  }
#pragma unroll
  for (int mi = 0; mi < 4; mi++)
#pragma unroll
    for (int ni = 0; ni < 4; ni++)
#pragma unroll
      for (int r = 0; r < 4; r++) {
        const int m = m0 + wm + mi * 16 + l4 * 4 + r;
        const int n = n0 + wn + ni * 16 + l15;
        C[(size_t)m * 2048 + n] = acc[mi][ni][r];
      }
}

// ---------- Fallback GEMMs (round-6 proven): B from f32 weights.

__global__ __launch_bounds__(256, 2)
void qkv_gemm_f32(const unsigned short* __restrict__ xb,
                  const float* __restrict__ Wq, const float* __restrict__ Wk,
                  const float* __restrict__ Wv, const float* __restrict__ cosb,
                  const float* __restrict__ sinb,
                  unsigned short* __restrict__ Qb, unsigned short* __restrict__ Kb,
                  unsigned short* __restrict__ Vtb) {
  __shared__ __align__(16) unsigned short As[128 * 64];
  __shared__ __align__(16) unsigned short Bs[128 * 72];
  const int t = threadIdx.x;
  const int wave = t >> 6, lane = t & 63;
  const int l15 = lane & 15, l4 = lane >> 4;
  const int wm = (wave >> 1) * 64, wn = (wave & 1) * 64;
  const int m0 = blockIdx.y * 128, n0 = blockIdx.x * 128;
  const int crow = t >> 3, ccol = (t & 7) * 8;
  const unsigned short* Ag = xb + (size_t)m0 * 2048;

  const float* Bg; int ntype;
  if (n0 < 2048)      { Bg = Wq + (size_t)n0 * 2048;          ntype = 0; }
  else if (n0 < 3072) { Bg = Wk + (size_t)(n0 - 2048) * 2048; ntype = 1; }
  else                { Bg = Wv + (size_t)(n0 - 3072) * 2048; ntype = 2; }

  const f32x4 fzero = {0.f, 0.f, 0.f, 0.f};
  f32x4 acc[4][4];
#pragma unroll
  for (int i = 0; i < 4; i++)
#pragma unroll
    for (int j = 0; j < 4; j++) acc[i][j] = fzero;

  float4 rbf[4][2];
#pragma unroll
  for (int i = 0; i < 4; i++) {
    rbf[i][0] = *(const float4*)(Bg + (size_t)(crow + 32 * i) * 2048 + ccol);
    rbf[i][1] = *(const float4*)(Bg + (size_t)(crow + 32 * i) * 2048 + ccol + 4);
  }
  for (int kt = 0; kt < 32; ++kt) {
    const int k0 = kt << 6;
    __syncthreads();
#pragma unroll
    for (int j = 0; j < 4; j++)
      GLOAD_LDS16(Ag + (size_t)(j * 32 + crow) * 2048 + k0 + ccol,
                  &As[j * 2048 + wave * 512]);
#pragma unroll
    for (int i = 0; i < 4; i++)
      *(short8*)(&Bs[(crow + 32 * i) * 72 + ccol]) = cvt8(rbf[i][0], rbf[i][1]);
    __syncthreads();
    if (kt + 1 < 32) {
      const int kn = k0 + 64;
#pragma unroll
      for (int i = 0; i < 4; i++) {
        rbf[i][0] = *(const float4*)(Bg + (size_t)(crow + 32 * i) * 2048 + kn + ccol);
        rbf[i][1] = *(const float4*)(Bg + (size_t)(crow + 32 * i) * 2048 + kn + ccol + 4);
      }
    }
#pragma unroll
    for (int ks = 0; ks < 2; ++ks) {
      short8 af[4], bfr[4];
#pragma unroll
      for (int mi = 0; mi < 4; mi++)
        af[mi] = *(const short8*)(&As[(wm + mi * 16 + l15) * 64 + ks * 32 + l4 * 8]);
#pragma unroll
      for (int ni = 0; ni < 4; ni++)
        bfr[ni] = *(const short8*)(&Bs[(wn + ni * 16 + l15) * 72 + ks * 32 + l4 * 8]);
#pragma unroll
      for (int mi = 0; mi < 4; mi++)
#pragma unroll
        for (int ni = 0; ni < 4; ni++)
          acc[mi][ni] = __builtin_amdgcn_mfma_f32_16x16x32_bf16(af[mi], bfr[ni], acc[mi][ni], 0, 0, 0);
    }
  }
#pragma unroll
  for (int mi = 0; mi < 4; mi++)
#pragma unroll
    for (int ni = 0; ni < 4; ni++)
#pragma unroll
      for (int r = 0; r < 4; r++) {
        const int m = m0 + wm + mi * 16 + l4 * 4 + r;
        const int n = n0 + wn + ni * 16 + l15;
        float fv = acc[mi][ni][r];
        if (ntype < 2) {
          const int s = m & 2047;
          const int j = (n & 63) >> 1;
          const float c = cosb[s * 32 + j];
          const float sn = sinb[s * 32 + j];
          const float p = __shfl_xor(fv, 1);
          fv = (n & 1) ? (p * sn + fv * c) : (fv * c - p * sn);
        }
        if (ntype == 0)
          Qb[(size_t)m * 2048 + n] = f2bf(fv);
        else if (ntype == 1)
          Kb[(size_t)m * 1024 + (n - 2048)] = f2bf(fv);
        else
          Vtb[((size_t)((m >> 11) * 1024 + (n - 3072))) * 2048 + (m & 2047)] = f2bf(fv);
      }
}

__global__ __launch_bounds__(256, 2)
void o_gemm_f32(const unsigned short* __restrict__ Ab, const float* __restrict__ Wo,
                float* __restrict__ C) {
  __shared__ __align__(16) unsigned short As[128 * 64];
  __shared__ __align__(16) unsigned short Bs[128 * 72];
  const int t = threadIdx.x;
  const int wave = t >> 6, lane = t & 63;
  const int l15 = lane & 15, l4 = lane >> 4;
  const int wm = (wave >> 1) * 64, wn = (wave & 1) * 64;
  const int m0 = blockIdx.y * 128, n0 = blockIdx.x * 128;
  const int crow = t >> 3, ccol = (t & 7) * 8;
  const unsigned short* Ag = Ab + (size_t)m0 * 2048;
  const float* Bg = Wo + (size_t)n0 * 2048;

  const f32x4 fzero = {0.f, 0.f, 0.f, 0.f};
  f32x4 acc[4][4];
#pragma unroll
  for (int i = 0; i < 4; i++)
#pragma unroll
    for (int j = 0; j < 4; j++) acc[i][j] = fzero;

  float4 rbf[4][2];
#pragma unroll
  for (int i = 0; i < 4; i++) {
    rbf[i][0] = *(const float4*)(Bg + (size_t)(crow + 32 * i) * 2048 + ccol);
    rbf[i][1] = *(const float4*)(Bg + (size_t)(crow + 32 * i) * 2048 + ccol + 4);
  }
  for (int kt = 0; kt < 32; ++kt) {
    const int k0 = kt << 6;
    __syncthreads();
#pragma unroll
    for (int j = 0; j < 4; j++)
      GLOAD_LDS16(Ag + (size_t)(j * 32 + crow) * 2048 + k0 + ccol,
                  &As[j * 2048 + wave * 512]);
#pragma unroll
    for (int i = 0; i < 4; i++)
      *(short8*)(&Bs[(crow + 32 * i) * 72 + ccol]) = cvt8(rbf[i][0], rbf[i][1]);
    __syncthreads();
    if (kt + 1 < 32) {
      const int kn = k0 + 64;
#pragma unroll
      for (int i = 0; i < 4; i++) {
        rbf[i][0] = *(const float4*)(Bg + (size_t)(crow + 32 * i) * 2048 + kn + ccol);
        rbf[i][1] = *(const float4*)(Bg + (size_t)(crow + 32 * i) * 2048 + kn + ccol + 4);
      }
    }
#pragma unroll
    for (int ks = 0; ks < 2; ++ks) {
      short8 af[4], bfr[4];
#pragma unroll
      for (int mi = 0; mi < 4; mi++)
        af[mi] = *(const short8*)(&As[(wm + mi * 16 + l15) * 64 + ks * 32 + l4 * 8]);
#pragma unroll
      for (int ni = 0; ni < 4; ni++)
        bfr[ni] = *(const short8*)(&Bs[(wn + ni * 16 + l15) * 72 + ks * 32 + l4 * 8]);
#pragma unroll
      for (int mi = 0; mi < 4; mi++)
#pragma unroll
        for (int ni = 0; ni < 4; ni++)
          acc[mi][ni] = __builtin_amdgcn_mfma_f32_16x16x32_bf16(af[mi], bfr[ni], acc[mi][ni], 0, 0, 0);
    }
  }
#pragma unroll
  for (int mi = 0; mi < 4; mi++)
#pragma unroll
    for (int ni = 0; ni < 4; ni++)
#pragma unroll
      for (int r = 0; r < 4; r++) {
        const int m = m0 + wm + mi * 16 + l4 * 4 + r;
        const int n = n0 + wn + ni * 16 + l15;
        C[(size_t)m * 2048 + n] = acc[mi][ni][r];
      }
}

// ---------- Fused differential flash attention.
//  This round: swapped QK^T — z = mfma(K_frag, Q_frag) puts P[q][k] with
//  q = l15 (lane-local row) and k = 16ct + 4*l4 + r (4 consecutive k per
//  lane). The 4 values pack lane-locally (2x v_cvt_pk_bf16_f32) and store
//  as ONE ds_write_b64 to the same canonical swizzled slot the b128 pf
//  read already uses: Ps[q][k ^ ((q&7)<<3)]. P-path: 32 b16 stores +
//  32 casts -> 8 b64 stores + 16 packed casts. PV / accL / epilogue /
//  mask logic unchanged (C-layouts are shape-determined).
__global__ __launch_bounds__(256, 2)
void attn_kernel(const unsigned short* __restrict__ Q,
                 const unsigned short* __restrict__ Kb,
                 const unsigned short* __restrict__ Vt,
                 unsigned short* __restrict__ Ab,
                 const float* __restrict__ lq1,
                 const float* __restrict__ lk1,
                 const float* __restrict__ lq2,
                 const float* __restrict__ lk2,
                 const float* __restrict__ wsub) {
  // Bijective XCD swizzle (512 blocks = 8 XCDs x 64): dispatch d -> work
  // w = (d%8)*64 + d/8, so each XCD owns 64 consecutive work ids = 2 full
  // (b,hk) K/V groups -> K/V fetched ~once per XCD.
  const int flat = blockIdx.y * 16 + blockIdx.x;
  const int w = ((flat & 7) << 6) | (flat >> 3);
  const int pi = w & 15;                     // 0..15
  const int bh = w >> 4;                     // b*16 + h
  const int b = bh >> 4, h = bh & 15, hk = h >> 1;

  __shared__ __align__(16) unsigned short Ks[2][2][64 * 64];  // [buf][c][kv][d]
  __shared__ __align__(16) unsigned short Vs[2][128 * 64];    // [buf][d][kv]
  __shared__ __align__(16) unsigned short Ps[64 * 64];        // [q][kv]

  const int t = threadIdx.x;                 // 0..255
  const int wave = t >> 6, lane = t & 63;
  const int l15 = lane & 15, l4 = lane >> 4;
  const int crow = t >> 3, ccol = (t & 7) * 8;   // crow 0..31
  const int swc = ccol ^ ((crow & 7) << 3);  // pre-swizzled source col for staging

  float s1 = 0.f, s2 = 0.f;
  for (int i = 0; i < 64; i++) {
    s1 += lq1[i] * lk1[i];
    s2 += lq2[i] * lk2[i];
  }
  const float lam = __expf(s1) - __expf(s2) + LAMBDA_INIT;

  float wv[8];
#pragma unroll
  for (int nt = 0; nt < 8; nt++) wv[nt] = wsub[nt * 16 + l15];

  // ones B-fragment: B[k][n] = (n==0) ? 1 : 0  (bf16 1.0 = 0x3F80)
  short8 onesf;
#pragma unroll
  for (int j = 0; j < 8; j++) onesf[j] = (l15 == 0) ? (short)0x3F80 : (short)0;

  const f32x4 fzero = {0.f, 0.f, 0.f, 0.f};
  const unsigned short* Kgb = Kb + ((size_t)(b * 2048)) * 1024 + 2 * hk * 64;
  const unsigned short* Vgb = Vt + ((size_t)((b * 8 + hk) * 128)) * 2048;

#define STAGE_KV(KT, BUF)                                                     \
  do {                                                                        \
    const int k0s = (KT) << 6;                                                \
    _Pragma("unroll")                                                         \
    for (int c_ = 0; c_ < 2; c_++)                                            \
      _Pragma("unroll")                                                       \
      for (int i_ = 0; i_ < 2; i_++)                                          \
        GLOAD_LDS16(Kgb + (size_t)(k0s + i_ * 32 + crow) * 1024 + c_ * 64 + swc, \
                    &Ks[BUF][c_][i_ * 2048 + wave * 512]);                    \
    _Pragma("unroll")                                                         \
    for (int i_ = 0; i_ < 4; i_++)                                            \
      GLOAD_LDS16(Vgb + (size_t)(i_ * 32 + crow) * 2048 + k0s + swc,          \
                  &Vs[BUF][i_ * 2048 + wave * 512]);                          \
  } while (0)

  for (int half = 0; half < 2; ++half) {
    const int qi = half ? (31 - pi) : pi;    // both halves together: 33 k-tiles/block
    const int q0 = qi * 64;
    const int nkt = qi + 1;

    // Q fragments, direct global->reg (rows are wave-exclusive: wave*16..+15).
    short8 qf[2][2];  // [c][ks]
#pragma unroll
    for (int c = 0; c < 2; c++)
#pragma unroll
      for (int ks = 0; ks < 2; ks++)
        qf[c][ks] = *(const short8*)(Q + ((size_t)(b * 2048 + q0 + wave * 16 + l15)) * 2048
                                       + (2 * h + c) * 64 + ks * 32 + l4 * 8);

    f32x4 accO[2][8];  // [c][nt]
    f32x4 accL[2];
#pragma unroll
    for (int c = 0; c < 2; c++) {
      accL[c] = fzero;
#pragma unroll
      for (int nt = 0; nt < 8; nt++) accO[c][nt] = fzero;
    }

    __syncthreads();          // prior half's readers done before buf0 overwrite
    STAGE_KV(0, 0);

    for (int kt = 0; kt < nkt; ++kt) {
      const int cur = kt & 1;
      __syncthreads();        // stage(kt) complete; prev compute's reads done
      if (kt + 1 < nkt) STAGE_KV(kt + 1, cur ^ 1);   // in flight during compute(kt)

      const unsigned short* Ksb0 = &Ks[cur][0][0];
      const unsigned short* Ksb1 = &Ks[cur][1][0];
      const unsigned short* Vsb  = &Vs[cur][0];
      const bool diag = (kt == qi);          // block-uniform

      // ---- swapped QK^T -> exp -> packed b64 P-store -> pf frags
      short8 pf[2][2];  // [c][ks]
      const int qrow_l = wave * 16 + l15;    // this lane's q row (in tile)
      const int prow_off = qrow_l * 64;
      const int psw = (l15 & 7) << 3;        // row-swizzle for q = qrow_l
#pragma unroll
      for (int c = 0; c < 2; c++) {
        const unsigned short* Ksb = c ? Ksb1 : Ksb0;
#pragma unroll
        for (int ct = 0; ct < 4; ct++) {
          const int kr = ct * 16 + l15;
          const int ksw = (kr & 7) << 3;
          const short8 kb0 = *(const short8*)(&Ksb[kr * 64 + ((l4 * 8) ^ ksw)]);
          const short8 kb1 = *(const short8*)(&Ksb[kr * 64 + ((32 + l4 * 8) ^ ksw)]);
          f32x4 z = fzero;
          z = __builtin_amdgcn_mfma_f32_16x16x32_bf16(kb0, qf[c][0], z, 0, 0, 0);
          z = __builtin_amdgcn_mfma_f32_16x16x32_bf16(kb1, qf[c][1], z, 0, 0, 0);
          // lane holds P[q=qrow_l][k = 16ct + 4*l4 + r]
          float e[4];
#pragma unroll
          for (int r = 0; r < 4; r++)
            // exp(0.125*z - 16) as exp2(z*0.125*log2e - 16*log2e)
            e[r] = exp2f(fmaf(z[r], 0.18033688011112042f, -23.083120654223414f));
          if (diag) {                        // uniform branch; k0 == q0 cancels
            const int kbase = ct * 16 + l4 * 4;
#pragma unroll
            for (int r = 0; r < 4; r++)
              if ((kbase + r) > qrow_l) e[r] = 0.f;
          }
          // pack 4 consecutive-k bf16 and store as one b64 (swizzle mask
          // bits>=3 never interact with +r carry: (base+r)^s == (base^s)+r)
          __hip_bfloat162 p01 = __float22bfloat162_rn(make_float2(e[0], e[1]));
          __hip_bfloat162 p23 = __float22bfloat162_rn(make_float2(e[2], e[3]));
          uint2 pw;
          __builtin_memcpy(&pw.x, &p01, 4);
          __builtin_memcpy(&pw.y, &p23, 4);
          *(uint2*)(&Ps[prow_off + ((ct * 16 + l4 * 4) ^ psw)]) = pw;
        }
        // Wave-local P round-trip (rows [wave*16, wave*16+16) exclusive to wave).
#pragma unroll
        for (int ks = 0; ks < 2; ks++)
          pf[c][ks] = *(const short8*)(&Ps[prow_off + ((ks * 32 + l4 * 8) ^ psw)]);
      }

      // ---- PV + row sums
      __builtin_amdgcn_s_setprio(1);
#pragma unroll
      for (int nt = 0; nt < 8; nt++) {
        const int vrow = nt * 16 + l15;
        const int vsw = (vrow & 7) << 3;
        const short8 v0 = *(const short8*)(&Vsb[vrow * 64 + ((l4 * 8) ^ vsw)]);
        const short8 v1 = *(const short8*)(&Vsb[vrow * 64 + ((32 + l4 * 8) ^ vsw)]);
        accO[0][nt] = __builtin_amdgcn_mfma_f32_16x16x32_bf16(pf[0][0], v0, accO[0][nt], 0, 0, 0);
        accO[0][nt] = __builtin_amdgcn_mfma_f32_16x16x32_bf16(pf[0][1], v1, accO[0][nt], 0, 0, 0);
        accO[1][nt] = __builtin_amdgcn_mfma_f32_16x16x32_bf16(pf[1][0], v0, accO[1][nt], 0, 0, 0);
        accO[1][nt] = __builtin_amdgcn_mfma_f32_16x16x32_bf16(pf[1][1], v1, accO[1][nt], 0, 0, 0);
      }
#pragma unroll
      for (int c = 0; c < 2; c++) {
        accL[c] = __builtin_amdgcn_mfma_f32_16x16x32_bf16(pf[c][0], onesf, accL[c], 0, 0, 0);
        accL[c] = __builtin_amdgcn_mfma_f32_16x16x32_bf16(pf[c][1], onesf, accL[c], 0, 0, 0);
      }
      __builtin_amdgcn_s_setprio(0);
    }

    // Epilogue: o1 - lam*o2, RMS-norm over 128, * subln_w * (1 - lambda_init).
#pragma unroll
    for (int r = 0; r < 4; r++) {
      const float l1 = __shfl(accL[0][r], lane & 48);
      const float l2 = __shfl(accL[1][r], lane & 48);
      const float i1 = 1.f / fmaxf(l1, 1e-30f);
      const float i2 = lam / fmaxf(l2, 1e-30f);
      float av[8], ss = 0.f;
#pragma unroll
      for (int nt = 0; nt < 8; nt++) {
        const float a = accO[0][nt][r] * i1 - accO[1][nt][r] * i2;
        av[nt] = a;
        ss += a * a;
      }
#pragma unroll
      for (int off = 1; off < 16; off <<= 1) ss += __shfl_xor(ss, off, 16);
      const float sca = rsqrtf(ss * (1.f / 128.f) + 1e-5f) * (1.f - LAMBDA_INIT);
      const int qrow = q0 + wave * 16 + l4 * 4 + r;
      unsigned short* Ao = Ab + ((size_t)(b * 2048 + qrow)) * 2048 + h * 128;
#pragma unroll
      for (int nt = 0; nt < 8; nt++)
        Ao[nt * 16 + l15] = f2bfn(av[nt] * sca * wv[nt]);
    }
  }
#undef STAGE_KV
}

extern "C" void kernel_launch(void* const* d_in, const int* in_sizes, int n_in,
                              void* d_out, int out_size, void* d_ws, size_t ws_size,
                              hipStream_t stream) {
  const float* x    = (const float*)d_in[0];
  const float* cosb = (const float*)d_in[1];
  const float* sinb = (const float*)d_in[2];
  const float* Wq   = (const float*)d_in[3];
  const float* Wk   = (const float*)d_in[4];
  const float* Wv   = (const float*)d_in[5];
  const float* Wo   = (const float*)d_in[6];
  const float* lq1  = (const float*)d_in[7];
  const float* lk1  = (const float*)d_in[8];
  const float* lq2  = (const float*)d_in[9];
  const float* lk2  = (const float*)d_in[10];
  const float* wsub = (const float*)d_in[11];
  float* out = (float*)d_out;

  // ws layout (fast, ws>=40MiB): [0,16) xb -> later A | [16,24) Wqb | [24,28) Wkb
  //   | [28,32) Wvb | [32,40) Wob.  Fallback (ws>=16MiB): [0,16) xb -> A.
  // d_out (32 MiB f32) temporarily hosts bf16 K(8) | Vt(8) | Q(16); O-GEMM
  // overwrites d_out with f32 C (K/Vt/Q dead by then).
  unsigned short* XA  = (unsigned short*)d_ws;
  unsigned short* Kb  = (unsigned short*)d_out;
  unsigned short* Vtb = Kb + (size_t)4096 * 1024;
  unsigned short* Qb  = Vtb + (size_t)2 * 1024 * 2048;

  dim3 blk(256);
  if (ws_size >= (size_t)41943040) {
    unsigned short* Wqb = XA + 8388608;
    unsigned short* Wkb = XA + 12582912;
    unsigned short* Wvb = XA + 14680064;
    unsigned short* Wob = XA + 16777216;
    conv_all<<<10240, blk, 0, stream>>>(x, Wq, Wk, Wv, Wo, XA);
    qkv_bb<<<dim3(32, 32), blk, 0, stream>>>(XA, Wqb, Wkb, Wvb, cosb, sinb, Qb, Kb, Vtb);
    attn_kernel<<<dim3(16, 32), blk, 0, stream>>>(Qb, Kb, Vtb, XA, lq1, lk1, lq2, lk2, wsub);
    o_bb<<<dim3(16, 32), blk, 0, stream>>>(XA, Wob, out);
  } else {
    conv_bf16<<<4096, blk, 0, stream>>>(x, XA, 1048576);
    qkv_gemm_f32<<<dim3(32, 32), blk, 0, stream>>>(XA, Wq, Wk, Wv, cosb, sinb, Qb, Kb, Vtb);
    attn_kernel<<<dim3(16, 32), blk, 0, stream>>>(Qb, Kb, Vtb, XA, lq1, lk1, lq2, lk2, wsub);
    o_gemm_f32<<<dim3(16, 32), blk, 0, stream>>>(XA, Wo, out);
  }
}